// Round 24
// baseline (381.575 us; speedup 1.0000x reference)
//
#include <hip/hip_runtime.h>
#include <hip/hip_bf16.h>
#include <math.h>

#define BB 128
#define CIN 256
#define COUT 512
#define TT 200
#define HH 8
#define KD 64
#define HK 512
#define HC 2048

typedef __hip_bfloat16 bf16;
typedef __attribute__((ext_vector_type(8))) short s16x8;
typedef __attribute__((ext_vector_type(4))) short s16x4;
typedef __attribute__((ext_vector_type(4))) float f32x4;

#define MFMA(a, b, c) __builtin_amdgcn_mfma_f32_16x16x32_bf16(a, b, c, 0, 0, 0)

__device__ __forceinline__ short bfs(float f) {
  bf16 h = __float2bfloat16(f);
  return *reinterpret_cast<short*>(&h);
}
__device__ __forceinline__ s16x8 ld8(const bf16* p) {
  return *reinterpret_cast<const s16x8*>(p);
}

// ---------------- K_prep (fused): wvp-fold | wc-pack | wqk-pack | xb-transpose ----------------
__global__ __launch_bounds__(256) void k_prep(const float* __restrict__ x,
    const float* __restrict__ Wq, const float* __restrict__ Wk,
    const float* __restrict__ Wv, const float* __restrict__ Wp, const float* __restrict__ bv,
    const float* __restrict__ Wc, const float* __restrict__ Wd,
    bf16* __restrict__ xb, bf16* __restrict__ xtb,
    bf16* __restrict__ WqT, bf16* __restrict__ WkT,
    bf16* __restrict__ WvpT, float* __restrict__ bvp,
    bf16* __restrict__ Wcb, bf16* __restrict__ Wdb) {
  __shared__ __align__(16) float smem[8736];
  int blk = blockIdx.x, tid = threadIdx.x;
  if (blk < 128) {
    float (*wpl)[256] = (float(*)[256])smem;
    float (*wvl)[32] = (float(*)[32])(smem + 8192);
    int h = blk >> 4, ci0 = (blk & 15) << 4;
    int c = tid;
    float acc[17];
#pragma unroll
    for (int i = 0; i < 17; ++i) acc[i] = 0.f;
    for (int p0 = 0; p0 < CIN; p0 += 32) {
      __syncthreads();
      for (int idx = c; idx < 17 * 32; idx += 256) {
        int pp = idx & 31, cil = idx >> 5;
        wvl[cil][pp] = (cil < 16) ? Wv[(size_t)(ci0 + cil) * HC + h * CIN + p0 + pp]
                                  : bv[h * CIN + p0 + pp];
      }
      for (int idx = c; idx < 32 * 256; idx += 256) {
        int cc = idx & 255, pp = idx >> 8;
        wpl[pp][cc] = Wp[(size_t)(h * CIN + p0 + pp) * CIN + cc];
      }
      __syncthreads();
#pragma unroll 4
      for (int pp = 0; pp < 32; ++pp) {
        float w = wpl[pp][c];
#pragma unroll
        for (int i = 0; i < 17; ++i) acc[i] += wvl[i][pp] * w;
      }
    }
    for (int i = 0; i < 16; ++i)
      WvpT[((size_t)h * CIN + c) * CIN + ci0 + i] = __float2bfloat16(acc[i]);
    if (ci0 == 0) bvp[h * CIN + c] = acc[16];
  } else if (blk < 640) {
    int o = blk - 128, i = tid;
    size_t oi = (size_t)o * CIN + i;
#pragma unroll
    for (int j = 0; j < 3; ++j)
      Wcb[(size_t)j * COUT * CIN + oi] = __float2bfloat16(Wc[oi * 3 + j]);
    Wdb[oi] = __float2bfloat16(Wd[oi]);
  } else if (blk < 1152) {
    int n = blk - 640, ci = tid;
    WqT[(size_t)n * CIN + ci] = __float2bfloat16(Wq[(size_t)ci * HK + n]);
    WkT[(size_t)n * CIN + ci] = __float2bfloat16(Wk[(size_t)ci * HK + n]);
  } else {
    float (*lx)[33] = (float(*)[33])smem;
    int xblk = blk - 1152, b = xblk / 7, tt = xblk % 7, t0 = tt * 32;
    const float* xbp = x + (size_t)b * CIN * TT;
    bf16* xo = xb + (size_t)b * 208 * CIN;
    bf16* xto = xtb + (size_t)b * CIN * 224;
    for (int idx = tid; idx < CIN * 32; idx += 256) {
      int c = idx >> 5, tl = idx & 31, t = t0 + tl;
      lx[c][tl] = (t < TT) ? xbp[(size_t)c * TT + t] : 0.f;
    }
    __syncthreads();
    for (int idx = tid; idx < CIN * 32; idx += 256) {
      int c = idx >> 5, tl = idx & 31;
      xto[(size_t)c * 224 + t0 + tl] = __float2bfloat16(lx[c][tl]);
    }
    for (int idx = tid; idx < 32 * 64; idx += 256) {
      int tl = idx >> 6, cs = idx & 63, t = t0 + tl;
      if (t < TT) {
        s16x4 p;
        p[0] = bfs(lx[cs * 4 + 0][tl]); p[1] = bfs(lx[cs * 4 + 1][tl]);
        p[2] = bfs(lx[cs * 4 + 2][tl]); p[3] = bfs(lx[cs * 4 + 3][tl]);
        *reinterpret_cast<s16x4*>(&xo[(size_t)t * CIN + cs * 4]) = p;
      }
    }
    if (tt == 6) {
      s16x4 z = {0, 0, 0, 0};
      for (int idx = tid; idx < 8 * 64; idx += 256) {
        int r = 200 + (idx >> 6), cs = idx & 63;
        *reinterpret_cast<s16x4*>(&xo[(size_t)r * CIN + cs * 4]) = z;
      }
    }
  }
}

// ---------------- K2 (MFMA): q,k = xb @ {WqT,WkT}^T + bias -> bf16 [b][t][HK] ----------------
__global__ __launch_bounds__(256) void k_qk(const bf16* __restrict__ xb,
    const bf16* __restrict__ WqT, const bf16* __restrict__ WkT,
    const float* __restrict__ bq, const float* __restrict__ bk,
    bf16* __restrict__ qo, bf16* __restrict__ kvo) {
  __shared__ short lt[208 * 72];   // 208 t-rows x 64 cols (stride 72)
  int blk = blockIdx.x, b = blk & 127, quad = blk >> 7;
  int tid = threadIdx.x, w = tid >> 6, l = tid & 63;
  int lrow = l & 15, g = l >> 4;
  int cw = quad * 64 + w * 16 + lrow;
  const bf16* xbb = xb + (size_t)b * 208 * CIN;
  const bf16* wqt = WqT + (size_t)cw * CIN;
  const bf16* wkt = WkT + (size_t)cw * CIN;
  f32x4 aq[13], ak[13];
#pragma unroll
  for (int mt = 0; mt < 13; ++mt) {
    aq[mt] = (f32x4){0.f, 0.f, 0.f, 0.f};
    ak[mt] = (f32x4){0.f, 0.f, 0.f, 0.f};
  }
  for (int kc = 0; kc < 8; ++kc) {
    int kof = kc * 32 + g * 8;
    s16x8 bqf = ld8(&wqt[kof]);
    s16x8 bkf = ld8(&wkt[kof]);
#pragma unroll
    for (int mt = 0; mt < 13; ++mt) {
      s16x8 afr = ld8(&xbb[(size_t)(mt * 16 + lrow) * CIN + kof]);
      aq[mt] = MFMA(afr, bqf, aq[mt]);
      ak[mt] = MFMA(afr, bkf, ak[mt]);
    }
  }
  float bqv = bq[cw], bkv = bk[cw];
  int colw = w * 16 + lrow;
#pragma unroll
  for (int mt = 0; mt < 13; ++mt)
#pragma unroll
    for (int r = 0; r < 4; ++r) {
      int t = mt * 16 + g * 4 + r;
      lt[t * 72 + colw] = bfs(aq[mt][r] + bqv);
    }
  __syncthreads();
  for (int idx = tid; idx < TT * 8; idx += 256) {
    int t = idx >> 3, ch = idx & 7;
    s16x8 v = *reinterpret_cast<const s16x8*>(&lt[t * 72 + ch * 8]);
    *reinterpret_cast<s16x8*>(&qo[((size_t)b * TT + t) * HK + quad * 64 + ch * 8]) = v;
  }
  __syncthreads();
#pragma unroll
  for (int mt = 0; mt < 13; ++mt)
#pragma unroll
    for (int r = 0; r < 4; ++r) {
      int t = mt * 16 + g * 4 + r;
      lt[t * 72 + colw] = bfs(ak[mt][r] + bkv);
    }
  __syncthreads();
  for (int idx = tid; idx < TT * 8; idx += 256) {
    int t = idx >> 3, ch = idx & 7;
    s16x8 v = *reinterpret_cast<const s16x8*>(&lt[t * 72 + ch * 8]);
    *reinterpret_cast<s16x8*>(&kvo[((size_t)b * TT + t) * HK + quad * 64 + ch * 8]) = v;
  }
}

// ---------------- K4 (MFMA): per-(b,h) causal scores + softmax -> att f32 + attb bf16 ---------
// lt stride 204 -> 3 blocks/CU. attb[bh][m][208]: bf16 copy for k_avx (cols 200-207 zero).
__global__ __launch_bounds__(256) void k_attn(const bf16* __restrict__ qo,
    const bf16* __restrict__ kvo, float* __restrict__ att, bf16* __restrict__ attb) {
  __shared__ __align__(16) float lt[4][16][204];
  int bh = blockIdx.x, b = bh >> 3, h = bh & 7;
  int tid = threadIdx.x, w = tid >> 6, l = tid & 63;
  int lrow = l & 15, g = l >> 4;
  const bf16* qb = qo + (size_t)b * TT * HK + h * KD;
  const bf16* kb = kvo + (size_t)b * TT * HK + h * KD;
  float* ab = att + (size_t)bh * TT * TT;
  bf16* abb = attb + (size_t)bh * TT * 208;
  const s16x8 z8 = {0, 0, 0, 0, 0, 0, 0, 0};
  for (int mt = w; mt < 13; mt += 4) {
    int ra = mt * 16 + lrow; if (ra > TT - 1) ra = TT - 1;
    s16x8 a0 = ld8(&qb[(size_t)ra * HK + g * 8]);
    s16x8 a1 = ld8(&qb[(size_t)ra * HK + 32 + g * 8]);
    f32x4 sacc[13];
#pragma unroll
    for (int st = 0; st < 13; ++st) sacc[st] = (f32x4){0.f, 0.f, 0.f, 0.f};
#pragma unroll
    for (int st = 0; st < 13; ++st) {
      if (st <= mt) {
        int rb = st * 16 + lrow; if (rb > TT - 1) rb = TT - 1;
        s16x8 b0 = ld8(&kb[(size_t)rb * HK + g * 8]);
        s16x8 b1 = ld8(&kb[(size_t)rb * HK + 32 + g * 8]);
        sacc[st] = MFMA(a0, b0, sacc[st]);
        sacc[st] = MFMA(a1, b1, sacc[st]);
      }
    }
#pragma unroll
    for (int r = 0; r < 4; ++r) {
      int m = mt * 16 + g * 4 + r;
      if (m >= TT) continue;
      float vals[13];
      float mx = -INFINITY;
#pragma unroll
      for (int st = 0; st < 13; ++st) {
        int col = st * 16 + lrow;
        float v = sacc[st][r] * 0.125f;
        vals[st] = (st <= mt && col <= m) ? v : -INFINITY;
        mx = fmaxf(mx, vals[st]);
      }
#pragma unroll
      for (int off = 1; off < 16; off <<= 1) mx = fmaxf(mx, __shfl_xor(mx, off));
      float e[13], sum = 0.f;
#pragma unroll
      for (int st = 0; st < 13; ++st) {
        e[st] = (vals[st] > -INFINITY) ? __expf(vals[st] - mx) : 0.f;
        sum += e[st];
      }
#pragma unroll
      for (int off = 1; off < 16; off <<= 1) sum += __shfl_xor(sum, off);
      float inv = 1.f / sum;
#pragma unroll
      for (int st = 0; st < 13; ++st) {
        if (st < 12 || lrow < 8)                       // col < 204 guard (col>=200 are zeros)
          lt[w][g * 4 + r][st * 16 + lrow] = e[st] * inv;
      }
    }
    __builtin_amdgcn_wave_barrier();
    // f32 att writeout: 16 rows x 50 float4
    for (int idx = l; idx < 16 * 50; idx += 64) {
      int row = idx / 50, ch = idx - row * 50;
      int m = mt * 16 + row;
      if (m < TT) {
        float4 v = *(const float4*)&lt[w][row][ch * 4];
        *(float4*)&ab[(size_t)m * TT + ch * 4] = v;
      }
    }
    // bf16 attb writeout: 16 rows x 26 s16x8 chunks (ch 25 = zeros for cols 200-207)
    for (int idx = l; idx < 16 * 26; idx += 64) {
      int row = idx / 26, ch = idx - row * 26;
      int m = mt * 16 + row;
      if (m < TT) {
        s16x8 v = z8;
        if (ch < 25) {
#pragma unroll
          for (int j = 0; j < 8; ++j) v[j] = bfs(lt[w][row][ch * 8 + j]);
        }
        *reinterpret_cast<s16x8*>(&abb[(size_t)m * 208 + ch * 8]) = v;
      }
    }
    __builtin_amdgcn_wave_barrier();
  }
}

// ---------------- K5 (MFMA, fused): atTp[t+4][c] = sum_h (att_h @ x^T) @ WvpT_h + biases -------
// 512 threads, causal-paired t-ranges, satt staged from bf16 attb (half the read bytes, no cvt).
__global__ __launch_bounds__(512) void k_avx(const bf16* __restrict__ attb,
    const bf16* __restrict__ xtb, const bf16* __restrict__ WvpT,
    const float* __restrict__ bvp, const float* __restrict__ bp,
    bf16* __restrict__ atTp) {
  __shared__ short satt[64 * 232];
  __shared__ short yl[64 * 260];
  int blk = blockIdx.x, b = blk & 127, p = blk >> 7;
  bool hasB = (p < 3);
  int rA = hasB ? p : 6, rB = 5 - p;
  int nsA = rA + 1, nsB = rB + 1;
  int nsTot = hasB ? nsB : nsA;
  int tid = threadIdx.x, w = tid >> 6, l = tid & 63;
  int lrow = l & 15, g = l >> 4;
  bf16* atb = atTp + (size_t)b * 216 * CIN;
  bf16 zb = __float2bfloat16(0.f);
  const s16x8 z8 = {0, 0, 0, 0, 0, 0, 0, 0};
  if (p == 0) { for (int idx = tid; idx < 4 * CIN; idx += 512) atb[idx] = zb; }
  if (p == 3) { for (int idx = tid; idx < 8 * CIN; idx += 512) atb[204 * CIN + idx] = zb; }
  const bf16* xr = xtb + (size_t)b * CIN * 224;
  int srow = tid >> 3, scid = tid & 7;
  int sT = (srow < 32) ? (rA * 32 + srow) : (rB * 32 + (srow - 32));
  if (sT > TT - 1) sT = TT - 1;
  int snrow = (srow < 32) ? nsA : nsB;   // causal s-tiles for this row
  bool sact = (srow < 32) || hasB;
  int nchunks = snrow * 4;               // 8-col bf16 chunks actually read for this row
  f32x4 acc2[4][2];
#pragma unroll
  for (int mt = 0; mt < 4; ++mt)
#pragma unroll
    for (int nt = 0; nt < 2; ++nt) acc2[mt][nt] = (f32x4){0.f, 0.f, 0.f, 0.f};
  for (int h = 0; h < HH; ++h) {
    const bf16* abb = attb + ((size_t)(b * HH + h) * TT + sT) * 208;
    __syncthreads();   // satt free (stage1 h-1 done) + stage2(h-1) yl reads complete
    if (sact) {
      for (int jj = 0; jj * 8 < nchunks; ++jj) {
        int ch = jj * 8 + scid;
        if (ch < nchunks) {
          s16x8 v = (ch < 26) ? ld8(&abb[ch * 8]) : z8;  // cols>=208 are zero pad
          *reinterpret_cast<s16x8*>(&satt[srow * 232 + ch * 8]) = v;
        }
      }
    }
    __syncthreads();   // satt visible
    f32x4 acc1[2][4];
#pragma unroll
    for (int mc = 0; mc < 2; ++mc)
#pragma unroll
      for (int nt = 0; nt < 4; ++nt) acc1[mc][nt] = (f32x4){0.f, 0.f, 0.f, 0.f};
    for (int ss = 0; ss < nsTot; ++ss) {
      int s0 = ss * 32;
      s16x8 af0 = ld8(&xr[(size_t)(w * 32 + lrow) * 224 + s0 + g * 8]);
      s16x8 af1 = ld8(&xr[(size_t)(w * 32 + 16 + lrow) * 224 + s0 + g * 8]);
      if (ss < nsA) {
        s16x8 b0 = *reinterpret_cast<const s16x8*>(&satt[(lrow) * 232 + s0 + g * 8]);
        s16x8 b1 = *reinterpret_cast<const s16x8*>(&satt[(16 + lrow) * 232 + s0 + g * 8]);
        acc1[0][0] = MFMA(af0, b0, acc1[0][0]);
        acc1[0][1] = MFMA(af0, b1, acc1[0][1]);
        acc1[1][0] = MFMA(af1, b0, acc1[1][0]);
        acc1[1][1] = MFMA(af1, b1, acc1[1][1]);
      }
      if (hasB && ss < nsB) {
        s16x8 b2 = *reinterpret_cast<const s16x8*>(&satt[(32 + lrow) * 232 + s0 + g * 8]);
        s16x8 b3 = *reinterpret_cast<const s16x8*>(&satt[(48 + lrow) * 232 + s0 + g * 8]);
        acc1[0][2] = MFMA(af0, b2, acc1[0][2]);
        acc1[0][3] = MFMA(af0, b3, acc1[0][3]);
        acc1[1][2] = MFMA(af1, b2, acc1[1][2]);
        acc1[1][3] = MFMA(af1, b3, acc1[1][3]);
      }
    }
    // yl write: per-thread dep on acc1 only; stage2(h-1) reads fenced 2 barriers ago.
#pragma unroll
    for (int mc = 0; mc < 2; ++mc)
#pragma unroll
      for (int nt = 0; nt < 4; ++nt) {
        s16x4 pk;
        pk[0] = bfs(acc1[mc][nt][0]); pk[1] = bfs(acc1[mc][nt][1]);
        pk[2] = bfs(acc1[mc][nt][2]); pk[3] = bfs(acc1[mc][nt][3]);
        *reinterpret_cast<s16x4*>(&yl[(nt * 16 + lrow) * 260 + w * 32 + mc * 16 + g * 4]) = pk;
      }
    __syncthreads();   // yl visible
    const bf16* wv = WvpT + (size_t)h * CIN * CIN;
#pragma unroll
    for (int kc = 0; kc < 8; ++kc) {
      int kof = kc * 32 + g * 8;
      s16x8 bw[2];
#pragma unroll
      for (int nt = 0; nt < 2; ++nt)
        bw[nt] = ld8(&wv[(size_t)(w * 32 + nt * 16 + lrow) * CIN + kof]);
#pragma unroll
      for (int mt = 0; mt < 4; ++mt) {
        s16x4 alo = *reinterpret_cast<const s16x4*>(&yl[(mt * 16 + lrow) * 260 + kof]);
        s16x4 ahi = *reinterpret_cast<const s16x4*>(&yl[(mt * 16 + lrow) * 260 + kof + 4]);
        s16x8 ay;
        ay[0] = alo[0]; ay[1] = alo[1]; ay[2] = alo[2]; ay[3] = alo[3];
        ay[4] = ahi[0]; ay[5] = ahi[1]; ay[6] = ahi[2]; ay[7] = ahi[3];
#pragma unroll
        for (int nt = 0; nt < 2; ++nt)
          acc2[mt][nt] = MFMA(ay, bw[nt], acc2[mt][nt]);
      }
    }
  }
#pragma unroll
  for (int nt = 0; nt < 2; ++nt) {
    int c = w * 32 + nt * 16 + lrow;
    float bsum = bp[c];
#pragma unroll
    for (int h = 0; h < HH; ++h) bsum += bvp[h * CIN + c];
#pragma unroll
    for (int mt = 0; mt < 4; ++mt) {
#pragma unroll
      for (int r = 0; r < 4; ++r) {
        int tloc = mt * 16 + g * 4 + r;
        int tg_; bool valid;
        if (tloc < 32) { tg_ = rA * 32 + tloc; valid = hasB || (tloc < 8); }
        else           { tg_ = rB * 32 + (tloc - 32); valid = hasB; }
        if (valid)
          atb[(size_t)(tg_ + 4) * CIN + c] = __float2bfloat16(acc2[mt][nt][r] + bsum);
      }
    }
  }
}

// ---------------- K6 (MFMA): dilated conv + residual, LDS-staged + T14 register prefetch ------
__global__ __launch_bounds__(256) void k_conv(const bf16* __restrict__ atTp,
    const bf16* __restrict__ xb, const bf16* __restrict__ Wcb, const bf16* __restrict__ Wdb,
    const float* __restrict__ bc, const float* __restrict__ bd, float* __restrict__ out0) {
  __shared__ short satb[116 * 64];
  __shared__ short sxb[112 * 64];
  int blk = blockIdx.x, b = blk & 127, og = (blk >> 7) & 7, th = blk >> 10;
  int t0 = th * 100;
  int tid = threadIdx.x, w = tid >> 6, l = tid & 63;
  int lrow = l & 15, g = l >> 4;
  int o0 = og * 64 + w * 16;
  const bf16* wc0 = Wcb + (size_t)(o0 + lrow) * CIN;
  const bf16* wc1 = wc0 + (size_t)COUT * CIN;
  const bf16* wc2 = wc1 + (size_t)COUT * CIN;
  const bf16* wdp = Wdb + (size_t)(o0 + lrow) * CIN;
  const bf16* atb = atTp + (size_t)b * 216 * CIN;
  const bf16* xbb = xb + (size_t)b * 208 * CIN;
  f32x4 accc[7], accr[7];
#pragma unroll
  for (int nt = 0; nt < 7; ++nt) {
    accc[nt] = (f32x4){0.f, 0.f, 0.f, 0.f};
    accr[nt] = (f32x4){0.f, 0.f, 0.f, 0.f};
  }
  s16x8 pa[4], px[4];
  const s16x8 z8 = {0, 0, 0, 0, 0, 0, 0, 0};
#pragma unroll
  for (int j = 0; j < 4; ++j) {
    int idx = tid + j * 256;
    pa[j] = z8; px[j] = z8;
    if (idx < 116 * 8) pa[j] = ld8(&atb[(size_t)(t0 + (idx >> 3)) * CIN + (idx & 7) * 8]);
    if (idx < 112 * 8) {
      int gx = t0 + (idx >> 3); if (gx > 207) gx = 207;
      px[j] = ld8(&xbb[(size_t)gx * CIN + (idx & 7) * 8]);
    }
  }
  for (int ks = 0; ks < 4; ++ks) {
    int kb0 = ks * 64;
    __syncthreads();
#pragma unroll
    for (int j = 0; j < 4; ++j) {
      int idx = tid + j * 256;
      if (idx < 116 * 8) {
        int row = idx >> 3, ch = idx & 7;
        *reinterpret_cast<s16x8*>(&satb[row * 64 + ((ch ^ (row & 7)) * 8)]) = pa[j];
      }
      if (idx < 112 * 8) {
        int row = idx >> 3, ch = idx & 7;
        *reinterpret_cast<s16x8*>(&sxb[row * 64 + ((ch ^ (row & 7)) * 8)]) = px[j];
      }
    }
    if (ks < 3) {
      int kb1 = kb0 + 64;
#pragma unroll
      for (int j = 0; j < 4; ++j) {
        int idx = tid + j * 256;
        if (idx < 116 * 8) pa[j] = ld8(&atb[(size_t)(t0 + (idx >> 3)) * CIN + kb1 + (idx & 7) * 8]);
        if (idx < 112 * 8) {
          int gx = t0 + (idx >> 3); if (gx > 207) gx = 207;
          px[j] = ld8(&xbb[(size_t)gx * CIN + kb1 + (idx & 7) * 8]);
        }
      }
    }
    __syncthreads();
#pragma unroll
    for (int kcl = 0; kcl < 2; ++kcl) {
      int kof = kb0 + kcl * 32 + g * 8;
      s16x8 a0 = ld8(&wc0[kof]);
      s16x8 a1 = ld8(&wc1[kof]);
      s16x8 a2 = ld8(&wc2[kof]);
      s16x8 ad = ld8(&wdp[kof]);
      int chb = kcl * 4 + g;
#pragma unroll
      for (int nt = 0; nt < 7; ++nt) {
        int r0 = nt * 16 + lrow, r1 = r0 + 2, r2 = r0 + 4;
        s16x8 b0 = *reinterpret_cast<const s16x8*>(&satb[r0 * 64 + ((chb ^ (r0 & 7)) * 8)]);
        s16x8 b1 = *reinterpret_cast<const s16x8*>(&satb[r1 * 64 + ((chb ^ (r1 & 7)) * 8)]);
        s16x8 b2 = *reinterpret_cast<const s16x8*>(&satb[r2 * 64 + ((chb ^ (r2 & 7)) * 8)]);
        s16x8 bx = *reinterpret_cast<const s16x8*>(&sxb[r0 * 64 + ((chb ^ (r0 & 7)) * 8)]);
        accc[nt] = MFMA(a0, b0, accc[nt]);
        accc[nt] = MFMA(a1, b1, accc[nt]);
        accc[nt] = MFMA(a2, b2, accc[nt]);
        accr[nt] = MFMA(ad, bx, accr[nt]);
      }
    }
  }
  f32x4 bcv = *reinterpret_cast<const f32x4*>(&bc[o0 + g * 4]);
  f32x4 bdv = *reinterpret_cast<const f32x4*>(&bd[o0 + g * 4]);
#pragma unroll
  for (int nt = 0; nt < 7; ++nt) {
    int tloc = nt * 16 + lrow;
    if (tloc < 100) {
      int t = t0 + tloc;
#pragma unroll
      for (int r = 0; r < 4; ++r) {
        int o = o0 + g * 4 + r;
        float conv = fmaxf(accc[nt][r] + bcv[r], 0.f);
        out0[((size_t)b * COUT + o) * TT + t] = fmaxf(conv + accr[nt][r] + bdv[r], 0.f);
      }
    }
  }
}

extern "C" void kernel_launch(void* const* d_in, const int* in_sizes, int n_in,
                              void* d_out, int out_size, void* d_ws, size_t ws_size,
                              hipStream_t stream) {
  const float* x  = (const float*)d_in[0];
  const float* Wq = (const float*)d_in[1];
  const float* bq = (const float*)d_in[2];
  const float* Wk = (const float*)d_in[3];
  const float* bk = (const float*)d_in[4];
  const float* Wv = (const float*)d_in[5];
  const float* bv = (const float*)d_in[6];
  const float* Wp = (const float*)d_in[7];
  const float* bp = (const float*)d_in[8];
  const float* Wc = (const float*)d_in[9];
  const float* bc = (const float*)d_in[10];
  const float* Wd = (const float*)d_in[11];
  const float* bd = (const float*)d_in[12];

  float* out0 = (float*)d_out;
  float* att  = out0 + (size_t)BB * COUT * TT;  // second output, (B,H,T,T)

  char* ws = (char*)d_ws;
  bf16*  qo   = (bf16*)(ws);                     // 26,214,400 B ([b][t][HK])
  bf16*  kvo  = (bf16*)(ws + 26214400);          // 26,214,400 B
  bf16*  xtb  = (bf16*)(ws + 52428800);          // 14,680,064 B  (B x 256 x 224)
  bf16*  atTp = (bf16*)(ws + 67108864);          // 14,155,776 B  (B x 216 x 256)
  bf16*  attb = (bf16*)(ws + 81264640);          // 85,196,800 B  (BH x 200 x 208)
  bf16*  xb   = (bf16*)(ws + 166461440);         // 13,631,488 B  (B x 208 x 256)
  bf16*  WvpT = (bf16*)(ws + 180092928);         // 1,048,576 B
  float* bvp  = (float*)(ws + 181141504);        // 8,192 B
  bf16*  Wcb  = (bf16*)(ws + 181149696);         // 786,432 B
  bf16*  Wdb  = (bf16*)(ws + 181936128);         // 262,144 B
  bf16*  WqT  = (bf16*)(ws + 182198272);         // 262,144 B
  bf16*  WkT  = (bf16*)(ws + 182460416);         // 262,144 B -> end 182,722,560 (<= 185.6MB proven)

  hipLaunchKernelGGL(k_prep, dim3(2048),     dim3(256), 0, stream,
                     x, Wq, Wk, Wv, Wp, bv, Wc, Wd, xb, xtb, WqT, WkT, WvpT, bvp, Wcb, Wdb);
  hipLaunchKernelGGL(k_qk,   dim3(BB * 8),   dim3(256), 0, stream, xb, WqT, WkT, bq, bk, qo, kvo);
  hipLaunchKernelGGL(k_attn, dim3(BB * HH),  dim3(256), 0, stream, qo, kvo, att, attb);
  hipLaunchKernelGGL(k_avx,  dim3(BB * 4),   dim3(512), 0, stream, attb, xtb, WvpT, bvp, bp, atTp);
  hipLaunchKernelGGL(k_conv, dim3(BB * 16),  dim3(256), 0, stream, atTp, xb, Wcb, Wdb, bc, bd, out0);
}

// Round 25
// 352.502 us; speedup vs baseline: 1.0825x; 1.0825x over previous
//
#include <hip/hip_runtime.h>
#include <hip/hip_bf16.h>
#include <math.h>

#define BB 128
#define CIN 256
#define COUT 512
#define TT 200
#define HH 8
#define KD 64
#define HK 512
#define HC 2048

typedef __hip_bfloat16 bf16;
typedef __attribute__((ext_vector_type(8))) short s16x8;
typedef __attribute__((ext_vector_type(4))) short s16x4;
typedef __attribute__((ext_vector_type(4))) float f32x4;

#define MFMA(a, b, c) __builtin_amdgcn_mfma_f32_16x16x32_bf16(a, b, c, 0, 0, 0)

__device__ __forceinline__ short bfs(float f) {
  bf16 h = __float2bfloat16(f);
  return *reinterpret_cast<short*>(&h);
}
__device__ __forceinline__ s16x8 ld8(const bf16* p) {
  return *reinterpret_cast<const s16x8*>(p);
}

// ---------------- K_prep (fused): wvp-fold | wc-pack | wqk-pack | xb-transpose ----------------
__global__ __launch_bounds__(256) void k_prep(const float* __restrict__ x,
    const float* __restrict__ Wq, const float* __restrict__ Wk,
    const float* __restrict__ Wv, const float* __restrict__ Wp, const float* __restrict__ bv,
    const float* __restrict__ Wc, const float* __restrict__ Wd,
    bf16* __restrict__ xb, bf16* __restrict__ xtb,
    bf16* __restrict__ WqT, bf16* __restrict__ WkT,
    bf16* __restrict__ WvpT, float* __restrict__ bvp,
    bf16* __restrict__ Wcb, bf16* __restrict__ Wdb) {
  __shared__ __align__(16) float smem[8736];
  int blk = blockIdx.x, tid = threadIdx.x;
  if (blk < 128) {
    float (*wpl)[256] = (float(*)[256])smem;
    float (*wvl)[32] = (float(*)[32])(smem + 8192);
    int h = blk >> 4, ci0 = (blk & 15) << 4;
    int c = tid;
    float acc[17];
#pragma unroll
    for (int i = 0; i < 17; ++i) acc[i] = 0.f;
    for (int p0 = 0; p0 < CIN; p0 += 32) {
      __syncthreads();
      for (int idx = c; idx < 17 * 32; idx += 256) {
        int pp = idx & 31, cil = idx >> 5;
        wvl[cil][pp] = (cil < 16) ? Wv[(size_t)(ci0 + cil) * HC + h * CIN + p0 + pp]
                                  : bv[h * CIN + p0 + pp];
      }
      for (int idx = c; idx < 32 * 256; idx += 256) {
        int cc = idx & 255, pp = idx >> 8;
        wpl[pp][cc] = Wp[(size_t)(h * CIN + p0 + pp) * CIN + cc];
      }
      __syncthreads();
#pragma unroll 4
      for (int pp = 0; pp < 32; ++pp) {
        float w = wpl[pp][c];
#pragma unroll
        for (int i = 0; i < 17; ++i) acc[i] += wvl[i][pp] * w;
      }
    }
    for (int i = 0; i < 16; ++i)
      WvpT[((size_t)h * CIN + c) * CIN + ci0 + i] = __float2bfloat16(acc[i]);
    if (ci0 == 0) bvp[h * CIN + c] = acc[16];
  } else if (blk < 640) {
    int o = blk - 128, i = tid;
    size_t oi = (size_t)o * CIN + i;
#pragma unroll
    for (int j = 0; j < 3; ++j)
      Wcb[(size_t)j * COUT * CIN + oi] = __float2bfloat16(Wc[oi * 3 + j]);
    Wdb[oi] = __float2bfloat16(Wd[oi]);
  } else if (blk < 1152) {
    int n = blk - 640, ci = tid;
    WqT[(size_t)n * CIN + ci] = __float2bfloat16(Wq[(size_t)ci * HK + n]);
    WkT[(size_t)n * CIN + ci] = __float2bfloat16(Wk[(size_t)ci * HK + n]);
  } else {
    float (*lx)[33] = (float(*)[33])smem;
    int xblk = blk - 1152, b = xblk / 7, tt = xblk % 7, t0 = tt * 32;
    const float* xbp = x + (size_t)b * CIN * TT;
    bf16* xo = xb + (size_t)b * 208 * CIN;
    bf16* xto = xtb + (size_t)b * CIN * 224;
    for (int idx = tid; idx < CIN * 32; idx += 256) {
      int c = idx >> 5, tl = idx & 31, t = t0 + tl;
      lx[c][tl] = (t < TT) ? xbp[(size_t)c * TT + t] : 0.f;
    }
    __syncthreads();
    for (int idx = tid; idx < CIN * 32; idx += 256) {
      int c = idx >> 5, tl = idx & 31;
      xto[(size_t)c * 224 + t0 + tl] = __float2bfloat16(lx[c][tl]);
    }
    for (int idx = tid; idx < 32 * 64; idx += 256) {
      int tl = idx >> 6, cs = idx & 63, t = t0 + tl;
      if (t < TT) {
        s16x4 p;
        p[0] = bfs(lx[cs * 4 + 0][tl]); p[1] = bfs(lx[cs * 4 + 1][tl]);
        p[2] = bfs(lx[cs * 4 + 2][tl]); p[3] = bfs(lx[cs * 4 + 3][tl]);
        *reinterpret_cast<s16x4*>(&xo[(size_t)t * CIN + cs * 4]) = p;
      }
    }
    if (tt == 6) {
      s16x4 z = {0, 0, 0, 0};
      for (int idx = tid; idx < 8 * 64; idx += 256) {
        int r = 200 + (idx >> 6), cs = idx & 63;
        *reinterpret_cast<s16x4*>(&xo[(size_t)r * CIN + cs * 4]) = z;
      }
    }
  }
}

// ---------------- K2 (MFMA): q,k = xb @ {WqT,WkT}^T + bias -> bf16 [b][t][HK] ----------------
// Epilogue stages accs through LDS -> dense 16B row stores.
__global__ __launch_bounds__(256) void k_qk(const bf16* __restrict__ xb,
    const bf16* __restrict__ WqT, const bf16* __restrict__ WkT,
    const float* __restrict__ bq, const float* __restrict__ bk,
    bf16* __restrict__ qo, bf16* __restrict__ kvo) {
  __shared__ short lt[208 * 72];   // 208 t-rows x 64 cols (stride 72)
  int blk = blockIdx.x, b = blk & 127, quad = blk >> 7;
  int tid = threadIdx.x, w = tid >> 6, l = tid & 63;
  int lrow = l & 15, g = l >> 4;
  int cw = quad * 64 + w * 16 + lrow;
  const bf16* xbb = xb + (size_t)b * 208 * CIN;
  const bf16* wqt = WqT + (size_t)cw * CIN;
  const bf16* wkt = WkT + (size_t)cw * CIN;
  f32x4 aq[13], ak[13];
#pragma unroll
  for (int mt = 0; mt < 13; ++mt) {
    aq[mt] = (f32x4){0.f, 0.f, 0.f, 0.f};
    ak[mt] = (f32x4){0.f, 0.f, 0.f, 0.f};
  }
  for (int kc = 0; kc < 8; ++kc) {
    int kof = kc * 32 + g * 8;
    s16x8 bqf = ld8(&wqt[kof]);
    s16x8 bkf = ld8(&wkt[kof]);
#pragma unroll
    for (int mt = 0; mt < 13; ++mt) {
      s16x8 afr = ld8(&xbb[(size_t)(mt * 16 + lrow) * CIN + kof]);
      aq[mt] = MFMA(afr, bqf, aq[mt]);
      ak[mt] = MFMA(afr, bkf, ak[mt]);
    }
  }
  float bqv = bq[cw], bkv = bk[cw];
  int colw = w * 16 + lrow;
#pragma unroll
  for (int mt = 0; mt < 13; ++mt)
#pragma unroll
    for (int r = 0; r < 4; ++r) {
      int t = mt * 16 + g * 4 + r;
      lt[t * 72 + colw] = bfs(aq[mt][r] + bqv);
    }
  __syncthreads();
  for (int idx = tid; idx < TT * 8; idx += 256) {
    int t = idx >> 3, ch = idx & 7;
    s16x8 v = *reinterpret_cast<const s16x8*>(&lt[t * 72 + ch * 8]);
    *reinterpret_cast<s16x8*>(&qo[((size_t)b * TT + t) * HK + quad * 64 + ch * 8]) = v;
  }
  __syncthreads();
#pragma unroll
  for (int mt = 0; mt < 13; ++mt)
#pragma unroll
    for (int r = 0; r < 4; ++r) {
      int t = mt * 16 + g * 4 + r;
      lt[t * 72 + colw] = bfs(ak[mt][r] + bkv);
    }
  __syncthreads();
  for (int idx = tid; idx < TT * 8; idx += 256) {
    int t = idx >> 3, ch = idx & 7;
    s16x8 v = *reinterpret_cast<const s16x8*>(&lt[t * 72 + ch * 8]);
    *reinterpret_cast<s16x8*>(&kvo[((size_t)b * TT + t) * HK + quad * 64 + ch * 8]) = v;
  }
}

// ---------------- K4 (MFMA): per-(b,h) causal scores + softmax -> att (f32, d_out) ------------
// lt stride 204 (52.2 KB) -> 3 blocks/CU. Cols >= 200 are masked zeros; the one store that
// would spill past stride 204 (st==12, lrow>=8) is skipped.
__global__ __launch_bounds__(256) void k_attn(const bf16* __restrict__ qo,
    const bf16* __restrict__ kvo, float* __restrict__ att) {
  __shared__ __align__(16) float lt[4][16][204];
  int bh = blockIdx.x, b = bh >> 3, h = bh & 7;
  int tid = threadIdx.x, w = tid >> 6, l = tid & 63;
  int lrow = l & 15, g = l >> 4;
  const bf16* qb = qo + (size_t)b * TT * HK + h * KD;
  const bf16* kb = kvo + (size_t)b * TT * HK + h * KD;
  float* ab = att + (size_t)bh * TT * TT;
  for (int mt = w; mt < 13; mt += 4) {
    int ra = mt * 16 + lrow; if (ra > TT - 1) ra = TT - 1;
    s16x8 a0 = ld8(&qb[(size_t)ra * HK + g * 8]);
    s16x8 a1 = ld8(&qb[(size_t)ra * HK + 32 + g * 8]);
    f32x4 sacc[13];
#pragma unroll
    for (int st = 0; st < 13; ++st) sacc[st] = (f32x4){0.f, 0.f, 0.f, 0.f};
#pragma unroll
    for (int st = 0; st < 13; ++st) {
      if (st <= mt) {
        int rb = st * 16 + lrow; if (rb > TT - 1) rb = TT - 1;
        s16x8 b0 = ld8(&kb[(size_t)rb * HK + g * 8]);
        s16x8 b1 = ld8(&kb[(size_t)rb * HK + 32 + g * 8]);
        sacc[st] = MFMA(a0, b0, sacc[st]);
        sacc[st] = MFMA(a1, b1, sacc[st]);
      }
    }
#pragma unroll
    for (int r = 0; r < 4; ++r) {
      int m = mt * 16 + g * 4 + r;
      if (m >= TT) continue;
      float vals[13];
      float mx = -INFINITY;
#pragma unroll
      for (int st = 0; st < 13; ++st) {
        int col = st * 16 + lrow;
        float v = sacc[st][r] * 0.125f;
        vals[st] = (st <= mt && col <= m) ? v : -INFINITY;
        mx = fmaxf(mx, vals[st]);
      }
#pragma unroll
      for (int off = 1; off < 16; off <<= 1) mx = fmaxf(mx, __shfl_xor(mx, off));
      float e[13], sum = 0.f;
#pragma unroll
      for (int st = 0; st < 13; ++st) {
        e[st] = (vals[st] > -INFINITY) ? __expf(vals[st] - mx) : 0.f;
        sum += e[st];
      }
#pragma unroll
      for (int off = 1; off < 16; off <<= 1) sum += __shfl_xor(sum, off);
      float inv = 1.f / sum;
#pragma unroll
      for (int st = 0; st < 13; ++st) {
        if (st < 12 || lrow < 8)                       // col < 204 guard (col>=200 are zeros)
          lt[w][g * 4 + r][st * 16 + lrow] = e[st] * inv;
      }
    }
    __builtin_amdgcn_wave_barrier();
    for (int idx = l; idx < 16 * 50; idx += 64) {
      int row = idx / 50, ch = idx - row * 50;
      int m = mt * 16 + row;
      if (m < TT) {
        float4 v = *(const float4*)&lt[w][row][ch * 4];
        *(float4*)&ab[(size_t)m * TT + ch * 4] = v;
      }
    }
    __builtin_amdgcn_wave_barrier();
  }
}

// ---------------- K5 (MFMA, fused): atTp[t+4][c] = sum_h (att_h @ x^T) @ WvpT_h + biases -------
// 512 threads, load-balanced causal pairing, 3 barriers/h (best measured config).
__global__ __launch_bounds__(512) void k_avx(const float* __restrict__ att,
    const bf16* __restrict__ xtb, const bf16* __restrict__ WvpT,
    const float* __restrict__ bvp, const float* __restrict__ bp,
    bf16* __restrict__ atTp) {
  __shared__ short satt[64 * 232];
  __shared__ short yl[64 * 260];
  int blk = blockIdx.x, b = blk & 127, p = blk >> 7;
  bool hasB = (p < 3);
  int rA = hasB ? p : 6, rB = 5 - p;
  int nsA = rA + 1, nsB = rB + 1;
  int nsTot = hasB ? nsB : nsA;
  int tid = threadIdx.x, w = tid >> 6, l = tid & 63;
  int lrow = l & 15, g = l >> 4;
  bf16* atb = atTp + (size_t)b * 216 * CIN;
  bf16 zb = __float2bfloat16(0.f);
  if (p == 0) { for (int idx = tid; idx < 4 * CIN; idx += 512) atb[idx] = zb; }
  if (p == 3) { for (int idx = tid; idx < 8 * CIN; idx += 512) atb[204 * CIN + idx] = zb; }
  const bf16* xr = xtb + (size_t)b * CIN * 224;
  int srow = tid >> 3, scid = tid & 7;
  int sT = (srow < 32) ? (rA * 32 + srow) : (rB * 32 + (srow - 32));
  if (sT > TT - 1) sT = TT - 1;
  int snrow = (srow < 32) ? nsA : nsB;
  bool sact = (srow < 32) || hasB;
  f32x4 acc2[4][2];
#pragma unroll
  for (int mt = 0; mt < 4; ++mt)
#pragma unroll
    for (int nt = 0; nt < 2; ++nt) acc2[mt][nt] = (f32x4){0.f, 0.f, 0.f, 0.f};
  for (int h = 0; h < HH; ++h) {
    const float* srcrow = att + (size_t)(b * HH + h) * TT * TT + (size_t)sT * TT;
    __syncthreads();   // satt free (stage1 h-1 done) + stage2(h-1) yl reads complete
    if (sact) {
      for (int jj = 0; jj < snrow; ++jj) {
        int ch = jj * 8 + scid;
        int col = ch * 4;
        float4 v = {0.f, 0.f, 0.f, 0.f};
        if (col < TT) v = *(const float4*)&srcrow[col];
        s16x4 pk;
        pk[0] = bfs(v.x); pk[1] = bfs(v.y); pk[2] = bfs(v.z); pk[3] = bfs(v.w);
        *reinterpret_cast<s16x4*>(&satt[srow * 232 + ch * 4]) = pk;
      }
    }
    __syncthreads();   // satt visible
    f32x4 acc1[2][4];
#pragma unroll
    for (int mc = 0; mc < 2; ++mc)
#pragma unroll
      for (int nt = 0; nt < 4; ++nt) acc1[mc][nt] = (f32x4){0.f, 0.f, 0.f, 0.f};
    for (int ss = 0; ss < nsTot; ++ss) {
      int s0 = ss * 32;
      s16x8 af0 = ld8(&xr[(size_t)(w * 32 + lrow) * 224 + s0 + g * 8]);
      s16x8 af1 = ld8(&xr[(size_t)(w * 32 + 16 + lrow) * 224 + s0 + g * 8]);
      if (ss < nsA) {
        s16x8 b0 = *reinterpret_cast<const s16x8*>(&satt[(lrow) * 232 + s0 + g * 8]);
        s16x8 b1 = *reinterpret_cast<const s16x8*>(&satt[(16 + lrow) * 232 + s0 + g * 8]);
        acc1[0][0] = MFMA(af0, b0, acc1[0][0]);
        acc1[0][1] = MFMA(af0, b1, acc1[0][1]);
        acc1[1][0] = MFMA(af1, b0, acc1[1][0]);
        acc1[1][1] = MFMA(af1, b1, acc1[1][1]);
      }
      if (hasB && ss < nsB) {
        s16x8 b2 = *reinterpret_cast<const s16x8*>(&satt[(32 + lrow) * 232 + s0 + g * 8]);
        s16x8 b3 = *reinterpret_cast<const s16x8*>(&satt[(48 + lrow) * 232 + s0 + g * 8]);
        acc1[0][2] = MFMA(af0, b2, acc1[0][2]);
        acc1[0][3] = MFMA(af0, b3, acc1[0][3]);
        acc1[1][2] = MFMA(af1, b2, acc1[1][2]);
        acc1[1][3] = MFMA(af1, b3, acc1[1][3]);
      }
    }
    // yl write: per-thread dep on acc1 only; stage2(h-1) reads fenced 2 barriers ago.
#pragma unroll
    for (int mc = 0; mc < 2; ++mc)
#pragma unroll
      for (int nt = 0; nt < 4; ++nt) {
        s16x4 pk;
        pk[0] = bfs(acc1[mc][nt][0]); pk[1] = bfs(acc1[mc][nt][1]);
        pk[2] = bfs(acc1[mc][nt][2]); pk[3] = bfs(acc1[mc][nt][3]);
        *reinterpret_cast<s16x4*>(&yl[(nt * 16 + lrow) * 260 + w * 32 + mc * 16 + g * 4]) = pk;
      }
    __syncthreads();   // yl visible
    const bf16* wv = WvpT + (size_t)h * CIN * CIN;
#pragma unroll
    for (int kc = 0; kc < 8; ++kc) {
      int kof = kc * 32 + g * 8;
      s16x8 bw[2];
#pragma unroll
      for (int nt = 0; nt < 2; ++nt)
        bw[nt] = ld8(&wv[(size_t)(w * 32 + nt * 16 + lrow) * CIN + kof]);
#pragma unroll
      for (int mt = 0; mt < 4; ++mt) {
        s16x4 alo = *reinterpret_cast<const s16x4*>(&yl[(mt * 16 + lrow) * 260 + kof]);
        s16x4 ahi = *reinterpret_cast<const s16x4*>(&yl[(mt * 16 + lrow) * 260 + kof + 4]);
        s16x8 ay;
        ay[0] = alo[0]; ay[1] = alo[1]; ay[2] = alo[2]; ay[3] = alo[3];
        ay[4] = ahi[0]; ay[5] = ahi[1]; ay[6] = ahi[2]; ay[7] = ahi[3];
#pragma unroll
        for (int nt = 0; nt < 2; ++nt)
          acc2[mt][nt] = MFMA(ay, bw[nt], acc2[mt][nt]);
      }
    }
  }
#pragma unroll
  for (int nt = 0; nt < 2; ++nt) {
    int c = w * 32 + nt * 16 + lrow;
    float bsum = bp[c];
#pragma unroll
    for (int h = 0; h < HH; ++h) bsum += bvp[h * CIN + c];
#pragma unroll
    for (int mt = 0; mt < 4; ++mt) {
#pragma unroll
      for (int r = 0; r < 4; ++r) {
        int tloc = mt * 16 + g * 4 + r;
        int tg_; bool valid;
        if (tloc < 32) { tg_ = rA * 32 + tloc; valid = hasB || (tloc < 8); }
        else           { tg_ = rB * 32 + (tloc - 32); valid = hasB; }
        if (valid)
          atb[(size_t)(tg_ + 4) * CIN + c] = __float2bfloat16(acc2[mt][nt][r] + bsum);
      }
    }
  }
}

// ---------------- K6 (MFMA): dilated conv + residual, LDS-staged + T14 register prefetch ------
__global__ __launch_bounds__(256) void k_conv(const bf16* __restrict__ atTp,
    const bf16* __restrict__ xb, const bf16* __restrict__ Wcb, const bf16* __restrict__ Wdb,
    const float* __restrict__ bc, const float* __restrict__ bd, float* __restrict__ out0) {
  __shared__ short satb[116 * 64];
  __shared__ short sxb[112 * 64];
  int blk = blockIdx.x, b = blk & 127, og = (blk >> 7) & 7, th = blk >> 10;
  int t0 = th * 100;
  int tid = threadIdx.x, w = tid >> 6, l = tid & 63;
  int lrow = l & 15, g = l >> 4;
  int o0 = og * 64 + w * 16;
  const bf16* wc0 = Wcb + (size_t)(o0 + lrow) * CIN;
  const bf16* wc1 = wc0 + (size_t)COUT * CIN;
  const bf16* wc2 = wc1 + (size_t)COUT * CIN;
  const bf16* wdp = Wdb + (size_t)(o0 + lrow) * CIN;
  const bf16* atb = atTp + (size_t)b * 216 * CIN;
  const bf16* xbb = xb + (size_t)b * 208 * CIN;
  f32x4 accc[7], accr[7];
#pragma unroll
  for (int nt = 0; nt < 7; ++nt) {
    accc[nt] = (f32x4){0.f, 0.f, 0.f, 0.f};
    accr[nt] = (f32x4){0.f, 0.f, 0.f, 0.f};
  }
  s16x8 pa[4], px[4];
  const s16x8 z8 = {0, 0, 0, 0, 0, 0, 0, 0};
#pragma unroll
  for (int j = 0; j < 4; ++j) {
    int idx = tid + j * 256;
    pa[j] = z8; px[j] = z8;
    if (idx < 116 * 8) pa[j] = ld8(&atb[(size_t)(t0 + (idx >> 3)) * CIN + (idx & 7) * 8]);
    if (idx < 112 * 8) {
      int gx = t0 + (idx >> 3); if (gx > 207) gx = 207;
      px[j] = ld8(&xbb[(size_t)gx * CIN + (idx & 7) * 8]);
    }
  }
  for (int ks = 0; ks < 4; ++ks) {
    int kb0 = ks * 64;
    __syncthreads();
#pragma unroll
    for (int j = 0; j < 4; ++j) {
      int idx = tid + j * 256;
      if (idx < 116 * 8) {
        int row = idx >> 3, ch = idx & 7;
        *reinterpret_cast<s16x8*>(&satb[row * 64 + ((ch ^ (row & 7)) * 8)]) = pa[j];
      }
      if (idx < 112 * 8) {
        int row = idx >> 3, ch = idx & 7;
        *reinterpret_cast<s16x8*>(&sxb[row * 64 + ((ch ^ (row & 7)) * 8)]) = px[j];
      }
    }
    if (ks < 3) {
      int kb1 = kb0 + 64;
#pragma unroll
      for (int j = 0; j < 4; ++j) {
        int idx = tid + j * 256;
        if (idx < 116 * 8) pa[j] = ld8(&atb[(size_t)(t0 + (idx >> 3)) * CIN + kb1 + (idx & 7) * 8]);
        if (idx < 112 * 8) {
          int gx = t0 + (idx >> 3); if (gx > 207) gx = 207;
          px[j] = ld8(&xbb[(size_t)gx * CIN + kb1 + (idx & 7) * 8]);
        }
      }
    }
    __syncthreads();
#pragma unroll
    for (int kcl = 0; kcl < 2; ++kcl) {
      int kof = kb0 + kcl * 32 + g * 8;
      s16x8 a0 = ld8(&wc0[kof]);
      s16x8 a1 = ld8(&wc1[kof]);
      s16x8 a2 = ld8(&wc2[kof]);
      s16x8 ad = ld8(&wdp[kof]);
      int chb = kcl * 4 + g;
#pragma unroll
      for (int nt = 0; nt < 7; ++nt) {
        int r0 = nt * 16 + lrow, r1 = r0 + 2, r2 = r0 + 4;
        s16x8 b0 = *reinterpret_cast<const s16x8*>(&satb[r0 * 64 + ((chb ^ (r0 & 7)) * 8)]);
        s16x8 b1 = *reinterpret_cast<const s16x8*>(&satb[r1 * 64 + ((chb ^ (r1 & 7)) * 8)]);
        s16x8 b2 = *reinterpret_cast<const s16x8*>(&satb[r2 * 64 + ((chb ^ (r2 & 7)) * 8)]);
        s16x8 bx = *reinterpret_cast<const s16x8*>(&sxb[r0 * 64 + ((chb ^ (r0 & 7)) * 8)]);
        accc[nt] = MFMA(a0, b0, accc[nt]);
        accc[nt] = MFMA(a1, b1, accc[nt]);
        accc[nt] = MFMA(a2, b2, accc[nt]);
        accr[nt] = MFMA(ad, bx, accr[nt]);
      }
    }
  }
  f32x4 bcv = *reinterpret_cast<const f32x4*>(&bc[o0 + g * 4]);
  f32x4 bdv = *reinterpret_cast<const f32x4*>(&bd[o0 + g * 4]);
#pragma unroll
  for (int nt = 0; nt < 7; ++nt) {
    int tloc = nt * 16 + lrow;
    if (tloc < 100) {
      int t = t0 + tloc;
#pragma unroll
      for (int r = 0; r < 4; ++r) {
        int o = o0 + g * 4 + r;
        float conv = fmaxf(accc[nt][r] + bcv[r], 0.f);
        out0[((size_t)b * COUT + o) * TT + t] = fmaxf(conv + accr[nt][r] + bdv[r], 0.f);
      }
    }
  }
}

extern "C" void kernel_launch(void* const* d_in, const int* in_sizes, int n_in,
                              void* d_out, int out_size, void* d_ws, size_t ws_size,
                              hipStream_t stream) {
  const float* x  = (const float*)d_in[0];
  const float* Wq = (const float*)d_in[1];
  const float* bq = (const float*)d_in[2];
  const float* Wk = (const float*)d_in[3];
  const float* bk = (const float*)d_in[4];
  const float* Wv = (const float*)d_in[5];
  const float* bv = (const float*)d_in[6];
  const float* Wp = (const float*)d_in[7];
  const float* bp = (const float*)d_in[8];
  const float* Wc = (const float*)d_in[9];
  const float* bc = (const float*)d_in[10];
  const float* Wd = (const float*)d_in[11];
  const float* bd = (const float*)d_in[12];

  float* out0 = (float*)d_out;
  float* att  = out0 + (size_t)BB * COUT * TT;  // second output, (B,H,T,T)

  char* ws = (char*)d_ws;
  // qo (dead after k_attn) shares space with atTp (written by k_avx)
  bf16*  qo   = (bf16*)(ws);                     // 26,214,400 B ([b][t][HK])
  bf16*  atTp = (bf16*)(ws);                     // 14,155,776 B  (B x 216 x 256)
  bf16*  kvo  = (bf16*)(ws + 26214400);          // 26,214,400 B ([b][t][HK])
  bf16*  xtb  = (bf16*)(ws + 52428800);          // 14,680,064 B  (B x 256 x 224)
  bf16*  xb   = (bf16*)(ws + 157286400);         // 13,631,488 B  (B x 208 x 256)
  bf16*  WvpT = (bf16*)(ws + 170917888);         // 1,048,576 B
  float* bvp  = (float*)(ws + 171966464);        // 8,192 B
  bf16*  Wcb  = (bf16*)(ws + 171974656);         // 786,432 B
  bf16*  Wdb  = (bf16*)(ws + 172761088);         // 262,144 B
  bf16*  WqT  = (bf16*)(ws + 173023232);         // 262,144 B
  bf16*  WkT  = (bf16*)(ws + 173285376);         // 262,144 B -> end 173,547,520

  hipLaunchKernelGGL(k_prep, dim3(2048),     dim3(256), 0, stream,
                     x, Wq, Wk, Wv, Wp, bv, Wc, Wd, xb, xtb, WqT, WkT, WvpT, bvp, Wcb, Wdb);
  hipLaunchKernelGGL(k_qk,   dim3(BB * 8),   dim3(256), 0, stream, xb, WqT, WkT, bq, bk, qo, kvo);
  hipLaunchKernelGGL(k_attn, dim3(BB * HH),  dim3(256), 0, stream, qo, kvo, att);
  hipLaunchKernelGGL(k_avx,  dim3(BB * 4),   dim3(512), 0, stream, att, xtb, WvpT, bvp, bp, atTp);
  hipLaunchKernelGGL(k_conv, dim3(BB * 16),  dim3(256), 0, stream, atTp, xb, Wcb, Wdb, bc, bd, out0);
}